// Round 6
// baseline (525.877 us; speedup 1.0000x reference)
//
#include <hip/hip_runtime.h>
#include <math.h>

#define B_   16
#define N_   4096
#define C_   512
#define CF_  256
#define NH_  8
#define HD_  32
#define FHD_ 128
#define BN_  (B_ * N_)   // 65536
#define EPS_ 1e-4f
#define PI2F 1.5707963267948966f

typedef _Float16 half8 __attribute__((ext_vector_type(8)));
typedef _Float16 half4 __attribute__((ext_vector_type(4)));
typedef float f32x4 __attribute__((ext_vector_type(4)));
typedef unsigned short u16x8 __attribute__((ext_vector_type(8)));

__device__ __forceinline__ float abs_clamp(float t) {
    float a = fminf(fmaxf(fabsf(t), 1e-4f), 1e4f);
    return t > 0.f ? a : (t < 0.f ? -a : 0.f);
}
__device__ __forceinline__ void gld16(const void* g, void* l) {
    __builtin_amdgcn_global_load_lds(
        (const __attribute__((address_space(1))) void*)g,
        (__attribute__((address_space(3))) void*)l, 16, 0, 0);
}

// ---------------------------------------------------------------- SE: mean over tokens + f32->f16 convert of query
__global__ __launch_bounds__(256) void se_sum_kernel(const float* __restrict__ q,
                                                     float* __restrict__ sesum,
                                                     _Float16* __restrict__ q16) {
    int b = blockIdx.x, chunk = blockIdx.y;   // chunk = 64 tokens
    int t = threadIdx.x;
    int c = (t & 127) * 4;
    int tok0 = chunk * 64 + (t >> 7) * 32;
    const float* p = q + ((size_t)b * N_ + tok0) * C_ + c;
    _Float16* o = q16 + ((size_t)b * N_ + tok0) * C_ + c;
    float a0 = 0.f, a1 = 0.f, a2 = 0.f, a3 = 0.f;
#pragma unroll 4
    for (int n = 0; n < 32; n++) {
        float4 v = *(const float4*)(p + (size_t)n * C_);
        a0 += v.x; a1 += v.y; a2 += v.z; a3 += v.w;
        half4 hv;
        hv[0] = (_Float16)v.x; hv[1] = (_Float16)v.y;
        hv[2] = (_Float16)v.z; hv[3] = (_Float16)v.w;
        *(half4*)(o + (size_t)n * C_) = hv;
    }
    atomicAdd(&sesum[b * C_ + c + 0], a0);
    atomicAdd(&sesum[b * C_ + c + 1], a1);
    atomicAdd(&sesum[b * C_ + c + 2], a2);
    atomicAdd(&sesum[b * C_ + c + 3], a3);
}

// ---------------------------------------------------------------- SE: 2-layer MLP + sigmoid
__global__ __launch_bounds__(256) void se_gate_kernel(const float* __restrict__ sesum,
                                                      const float* __restrict__ Wse1,
                                                      const float* __restrict__ Wse2,
                                                      float* __restrict__ segate) {
    __shared__ float sm[C_];
    __shared__ float hm[C_ / 2];
    int b = blockIdx.x, t = threadIdx.x;
    sm[t]       = sesum[b * C_ + t]       * (1.f / N_);
    sm[t + 256] = sesum[b * C_ + t + 256] * (1.f / N_);
    __syncthreads();
    {
        const float* w = Wse1 + (size_t)t * C_;
        float acc = 0.f;
        for (int c2 = 0; c2 < C_; c2++) acc += sm[c2] * w[c2];
        hm[t] = fmaxf(acc, 0.f);
    }
    __syncthreads();
    for (int r = 0; r < 2; r++) {
        int c2 = t + r * 256;
        const float* w2 = Wse2 + (size_t)c2 * (C_ / 2);
        float a2 = 0.f;
        for (int j = 0; j < C_ / 2; j++) a2 += hm[j] * w2[j];
        segate[b * C_ + c2] = 1.f / (1.f + expf(-a2));
    }
}

// ---------------------------------------------------------------- weight convert to f16
__global__ __launch_bounds__(256) void convert_w(const float* __restrict__ Wq,
                                                 const float* __restrict__ Wk,
                                                 const float* __restrict__ Wv,
                                                 const float* __restrict__ Wo,
                                                 _Float16* __restrict__ wcat,
                                                 _Float16* __restrict__ wo16) {
    int i = blockIdx.x * 256 + threadIdx.x;
    if (i < 768 * 512) {
        int r = i >> 9, c = i & 511;
        float w = (r < 256) ? Wq[(size_t)r * 512 + c]
                : (r < 512) ? Wk[(size_t)(r - 256) * 512 + c]
                            : Wv[(size_t)(r - 512) * 512 + c];
        wcat[i] = (_Float16)w;
    } else {
        int j = i - 768 * 512;
        wo16[j] = (_Float16)Wo[j];
    }
}

// ---------------------------------------------------------------- q/k/v projection GEMM
// 256 threads, tile 128x128, K=512. 3-buffer LDS pipeline with counted
// vmcnt(4) + raw s_barrier (one barrier per K-step): loads for tile it+2 are
// issued right after the barrier of step it, and each wave waits only its own
// tile-it loads (vmcnt(4) leaves the tile-it+1 group in flight). WAR safety:
// barrier(it) orders all step-it-1 reads before writes(it+2) to that buffer.
__global__ __launch_bounds__(256) void gemm_qkv(
    const _Float16* __restrict__ A16, const _Float16* __restrict__ Bw,
    const float* __restrict__ bq, const float* __restrict__ bk, const float* __restrict__ bv,
    _Float16* __restrict__ Oq, _Float16* __restrict__ kT, _Float16* __restrict__ vT) {
    constexpr int K = 512;
    constexpr int NITER = K / 32;   // 16

    __shared__ __align__(16) unsigned short As[3][128 * 32];   // 3 x 8 KB
    __shared__ __align__(16) unsigned short Bs[3][128 * 32];   // 3 x 8 KB

    const int t = threadIdx.x;
    const int did = blockIdx.x + 6 * blockIdx.y;
    const int lid = (did & 7) * 384 + (did >> 3);
    const int bx = lid % 6;
    const int Mb = (lid / 6) * 128;
    const int nrow0 = bx * 128;

    const int lane = t & 63;
    const int wv = t >> 6;
    const int mq = (wv >> 1) * 64;
    const int nq = (wv & 1) * 64;
    const int mrow = lane & 15;
    const int kq = lane >> 4;
    const int fragoff = mrow * 32 + ((kq ^ ((mrow >> 1) & 3)) * 8);

    const unsigned char *asrc0, *asrc1, *bsrc0, *bsrc1;
    int off0, off1;
    {
        int cid0 = t, cid1 = t + 256;
        int m0 = cid0 >> 2, c0 = (cid0 & 3) ^ ((m0 >> 1) & 3);
        int m1 = cid1 >> 2, c1 = (cid1 & 3) ^ ((m1 >> 1) & 3);
        asrc0 = (const unsigned char*)(A16 + (size_t)(Mb + m0) * K + c0 * 8);
        asrc1 = (const unsigned char*)(A16 + (size_t)(Mb + m1) * K + c1 * 8);
        bsrc0 = (const unsigned char*)(Bw + (size_t)(nrow0 + m0) * K + c0 * 8);
        bsrc1 = (const unsigned char*)(Bw + (size_t)(nrow0 + m1) * K + c1 * 8);
        off0 = cid0 * 8;
        off1 = cid1 * 8;
    }

    f32x4 acc[4][4];
#pragma unroll
    for (int mi = 0; mi < 4; mi++)
#pragma unroll
        for (int ni = 0; ni < 4; ni++) acc[mi][ni] = (f32x4){0.f, 0.f, 0.f, 0.f};

    // prologue: issue tiles 0 and 1
    gld16(asrc0, &As[0][off0]);
    gld16(asrc1, &As[0][off1]);
    gld16(bsrc0, &Bs[0][off0]);
    gld16(bsrc1, &Bs[0][off1]);
    gld16(asrc0 + 64, &As[1][off0]);
    gld16(asrc1 + 64, &As[1][off1]);
    gld16(bsrc0 + 64, &Bs[1][off0]);
    gld16(bsrc1 + 64, &Bs[1][off1]);

    int cur = 0;
#pragma unroll 1
    for (int it = 0; it < NITER; ++it) {
        if (it + 1 < NITER) {
            asm volatile("s_waitcnt vmcnt(4)" ::: "memory");
        } else {
            asm volatile("s_waitcnt vmcnt(0)" ::: "memory");
        }
        __builtin_amdgcn_sched_barrier(0);
        __builtin_amdgcn_s_barrier();
        if (it + 2 < NITER) {
            int nb = cur + 2; if (nb >= 3) nb -= 3;
            gld16(asrc0 + (it + 2) * 64, &As[nb][off0]);
            gld16(asrc1 + (it + 2) * 64, &As[nb][off1]);
            gld16(bsrc0 + (it + 2) * 64, &Bs[nb][off0]);
            gld16(bsrc1 + (it + 2) * 64, &Bs[nb][off1]);
        }

        half8 ah[4], bh[4];
#pragma unroll
        for (int mi = 0; mi < 4; mi++)
            ah[mi] = *(const half8*)&As[cur][(mq + mi * 16) * 32 + fragoff];
#pragma unroll
        for (int ni = 0; ni < 4; ni++)
            bh[ni] = *(const half8*)&Bs[cur][(nq + ni * 16) * 32 + fragoff];
#pragma unroll
        for (int mi = 0; mi < 4; mi++)
#pragma unroll
            for (int ni = 0; ni < 4; ni++)
                acc[mi][ni] = __builtin_amdgcn_mfma_f32_16x16x32_f16(ah[mi], bh[ni], acc[mi][ni], 0, 0, 0);

        cur = (cur == 2) ? 0 : cur + 1;
    }

#pragma unroll
    for (int ni = 0; ni < 4; ni++) {
        int gc = nrow0 + nq + ni * 16 + mrow;
        int mat = gc >> 8;
        int col = gc & 255;
        float bb = (mat == 0 ? bq : mat == 1 ? bk : bv)[col];
        if (mat == 0) {
#pragma unroll
            for (int mi = 0; mi < 4; mi++)
#pragma unroll
                for (int r = 0; r < 4; r++) {
                    int m = Mb + mq + mi * 16 + kq * 4 + r;
                    float v2 = fmaxf(acc[mi][ni][r] + bb, 0.f);
                    Oq[(size_t)m * CF_ + col] = (_Float16)v2;
                }
        } else {
            _Float16* OT = (mat == 1) ? kT : vT;
#pragma unroll
            for (int mi = 0; mi < 4; mi++) {
                int m0r = Mb + mq + mi * 16 + kq * 4;
                half4 hv;
#pragma unroll
                for (int r = 0; r < 4; r++) {
                    float v2 = acc[mi][ni][r] + bb;
                    if (mat == 1) v2 = fmaxf(v2, 0.f);
                    hv[r] = (_Float16)v2;
                }
                *(half4*)&OT[(size_t)col * BN_ + m0r] = hv;
            }
        }
    }
}

// ---------------------------------------------------------------- output projection GEMM
// Same 3-buffer counted-vmcnt pipeline, K=256 (8 steps).
__global__ __launch_bounds__(256) void gemm_out(
    const _Float16* __restrict__ A16, const _Float16* __restrict__ Bw,
    const float* __restrict__ bo, const float* __restrict__ sg,
    float* __restrict__ Of) {
    constexpr int K = 256;
    constexpr int NITER = K / 32;   // 8

    __shared__ __align__(16) unsigned short As[3][128 * 32];
    __shared__ __align__(16) unsigned short Bs[3][128 * 32];

    const int t = threadIdx.x;
    const int did = blockIdx.x + 4 * blockIdx.y;
    const int lid = (did & 7) * 256 + (did >> 3);
    const int bx = lid & 3;
    const int Mb = (lid >> 2) * 128;
    const int nrow0 = bx * 128;

    const int lane = t & 63;
    const int wv = t >> 6;
    const int mq = (wv >> 1) * 64;
    const int nq = (wv & 1) * 64;
    const int mrow = lane & 15;
    const int kq = lane >> 4;
    const int fragoff = mrow * 32 + ((kq ^ ((mrow >> 1) & 3)) * 8);

    const unsigned char *asrc0, *asrc1, *bsrc0, *bsrc1;
    int off0, off1;
    {
        int cid0 = t, cid1 = t + 256;
        int m0 = cid0 >> 2, c0 = (cid0 & 3) ^ ((m0 >> 1) & 3);
        int m1 = cid1 >> 2, c1 = (cid1 & 3) ^ ((m1 >> 1) & 3);
        asrc0 = (const unsigned char*)(A16 + (size_t)(Mb + m0) * K + c0 * 8);
        asrc1 = (const unsigned char*)(A16 + (size_t)(Mb + m1) * K + c1 * 8);
        bsrc0 = (const unsigned char*)(Bw + (size_t)(nrow0 + m0) * K + c0 * 8);
        bsrc1 = (const unsigned char*)(Bw + (size_t)(nrow0 + m1) * K + c1 * 8);
        off0 = cid0 * 8;
        off1 = cid1 * 8;
    }

    f32x4 acc[4][4];
#pragma unroll
    for (int mi = 0; mi < 4; mi++)
#pragma unroll
        for (int ni = 0; ni < 4; ni++) acc[mi][ni] = (f32x4){0.f, 0.f, 0.f, 0.f};

    gld16(asrc0, &As[0][off0]);
    gld16(asrc1, &As[0][off1]);
    gld16(bsrc0, &Bs[0][off0]);
    gld16(bsrc1, &Bs[0][off1]);
    gld16(asrc0 + 64, &As[1][off0]);
    gld16(asrc1 + 64, &As[1][off1]);
    gld16(bsrc0 + 64, &Bs[1][off0]);
    gld16(bsrc1 + 64, &Bs[1][off1]);

    int cur = 0;
#pragma unroll 1
    for (int it = 0; it < NITER; ++it) {
        if (it + 1 < NITER) {
            asm volatile("s_waitcnt vmcnt(4)" ::: "memory");
        } else {
            asm volatile("s_waitcnt vmcnt(0)" ::: "memory");
        }
        __builtin_amdgcn_sched_barrier(0);
        __builtin_amdgcn_s_barrier();
        if (it + 2 < NITER) {
            int nb = cur + 2; if (nb >= 3) nb -= 3;
            gld16(asrc0 + (it + 2) * 64, &As[nb][off0]);
            gld16(asrc1 + (it + 2) * 64, &As[nb][off1]);
            gld16(bsrc0 + (it + 2) * 64, &Bs[nb][off0]);
            gld16(bsrc1 + (it + 2) * 64, &Bs[nb][off1]);
        }

        half8 ah[4], bh[4];
#pragma unroll
        for (int mi = 0; mi < 4; mi++)
            ah[mi] = *(const half8*)&As[cur][(mq + mi * 16) * 32 + fragoff];
#pragma unroll
        for (int ni = 0; ni < 4; ni++)
            bh[ni] = *(const half8*)&Bs[cur][(nq + ni * 16) * 32 + fragoff];
#pragma unroll
        for (int mi = 0; mi < 4; mi++)
#pragma unroll
            for (int ni = 0; ni < 4; ni++)
                acc[mi][ni] = __builtin_amdgcn_mfma_f32_16x16x32_f16(ah[mi], bh[ni], acc[mi][ni], 0, 0, 0);

        cur = (cur == 2) ? 0 : cur + 1;
    }

    int b = Mb >> 12;
#pragma unroll
    for (int ni = 0; ni < 4; ni++) {
        int gc = nrow0 + nq + ni * 16 + mrow;
        float bb = bo[gc];
        float gv = sg[b * C_ + gc];
#pragma unroll
        for (int mi = 0; mi < 4; mi++)
#pragma unroll
            for (int r = 0; r < 4; r++) {
                int m = Mb + mq + mi * 16 + kq * 4 + r;
                float v2 = abs_clamp(acc[mi][ni][r] + bb);
                v2 = abs_clamp(v2 * (1.f + gv));
                Of[(size_t)m * C_ + gc] = v2;
            }
    }
}

// ---------------------------------------------------------------- kv state + k_sum via f16 MFMA
// All 8 k/v vector loads hoisted to kernel start (T14): only chunk-0 latency
// exposed; the rest hides under LDS staging + MFMA. Chunk loop fully unrolled
// so kk/vv indices are compile-time (rule #20).
__global__ __launch_bounds__(256) void kv_mfma_kernel(const _Float16* __restrict__ kin,
                                                      const _Float16* __restrict__ vin,
                                                      float* __restrict__ kvout,
                                                      float* __restrict__ ksum) {
    __shared__ __align__(16) unsigned short Ah[128 * 128];   // 32 KB
    __shared__ __align__(16) unsigned short Bh[48 * 128];    // 12 KB

    const int t = threadIdx.x;
    const int c8 = blockIdx.x;           // 512-token slab
    const int h = blockIdx.y, b = blockIdx.z;
    const int dp = t & 31;               // channel within head
    const int oct = t >> 5;              // token octet 0..7

    // constant rows 32..47: row 32 = ones(f16), rest zero
    {
        int r = 32 + (t >> 4);
        int c = t & 15;
        unsigned short fill = (r == 32) ? (unsigned short)0x3C00 : (unsigned short)0;
        u16x8 z = {fill, fill, fill, fill, fill, fill, fill, fill};
        *(u16x8*)&Bh[r * 128 + ((c ^ (r & 7)) * 8)] = z;
    }

    float cbv[8], sbv[8];
#pragma unroll
    for (int i = 0; i < 8; i++) {
        float ang = (PI2F / 64.f) * (float)(oct * 8 + i);
        cbv[i] = cosf(ang);
        sbv[i] = sinf(ang);
    }

    const int lane = t & 63;
    const int wv = t >> 6;
    const int mrow = lane & 15;
    const int kq = lane >> 4;

    f32x4 acc[2][3];
#pragma unroll
    for (int mi = 0; mi < 2; mi++)
#pragma unroll
        for (int ni = 0; ni < 3; ni++) acc[mi][ni] = (f32x4){0.f, 0.f, 0.f, 0.f};

    int offAa[4], offAb[4];
#pragma unroll
    for (int tvar = 0; tvar < 4; tvar++) {
        int f = tvar * 32 + dp;
        offAa[tvar] = f * 128 + ((oct ^ (f & 7)) * 8);
        offAb[tvar] = f * 128 + (((oct + 8) ^ (f & 7)) * 8);
    }
    const int offBa = dp * 128 + ((oct ^ (dp & 7)) * 8);
    const int offBb = dp * 128 + (((oct + 8) ^ (dp & 7)) * 8);

    const size_t colbase = (size_t)(h * HD_ + dp) * BN_ + (size_t)b * N_;

    // upfront loads of all 4 chunks (2 half8 each for k and v)
    half8 kk[4][2], vv[4][2];
    {
        const _Float16* kp0 = kin + colbase + c8 * 512 + oct * 8;
        const _Float16* vp0 = vin + colbase + c8 * 512 + oct * 8;
#pragma unroll
        for (int ch = 0; ch < 4; ch++) {
            kk[ch][0] = *(const half8*)(kp0 + ch * 128);
            kk[ch][1] = *(const half8*)(kp0 + ch * 128 + 64);
            vv[ch][0] = *(const half8*)(vp0 + ch * 128);
            vv[ch][1] = *(const half8*)(vp0 + ch * 128 + 64);
        }
    }

#pragma unroll
    for (int ch = 0; ch < 4; ch++) {
        const int n0 = c8 * 512 + ch * 128;
        const int rr = n0 >> 6;
        float ca0 = cosf((PI2F / 64.f) * (float)rr),       sa0 = sinf((PI2F / 64.f) * (float)rr);
        float ca1 = cosf((PI2F / 64.f) * (float)(rr + 1)), sa1 = sinf((PI2F / 64.f) * (float)(rr + 1));

        float ka[8], kb[8];
#pragma unroll
        for (int i = 0; i < 8; i++) { ka[i] = (float)kk[ch][0][i]; kb[i] = (float)kk[ch][1][i]; }

        __syncthreads();   // previous chunk's fragment reads done

#pragma unroll
        for (int tvar = 0; tvar < 4; tvar++) {
            half8 ha, hb;
#pragma unroll
            for (int i = 0; i < 8; i++) {
                float fa = (tvar == 0) ? ca0 : (tvar == 1) ? sa0 : (tvar == 2) ? cbv[i] : sbv[i];
                float fb = (tvar == 0) ? ca1 : (tvar == 1) ? sa1 : (tvar == 2) ? cbv[i] : sbv[i];
                ha[i] = (_Float16)(ka[i] * fa);
                hb[i] = (_Float16)(kb[i] * fb);
            }
            *(half8*)&Ah[offAa[tvar]] = ha;
            *(half8*)&Ah[offAb[tvar]] = hb;
        }
        *(half8*)&Bh[offBa] = vv[ch][0];
        *(half8*)&Bh[offBb] = vv[ch][1];
        __syncthreads();

#pragma unroll
        for (int s = 0; s < 4; s++) {
            int koct = s * 4 + kq;
            half8 ah[2], bh[3];
#pragma unroll
            for (int mi = 0; mi < 2; mi++) {
                int f = (wv * 2 + mi) * 16 + mrow;
                ah[mi] = *(const half8*)&Ah[f * 128 + ((koct ^ (f & 7)) * 8)];
            }
#pragma unroll
            for (int ni = 0; ni < 3; ni++) {
                int nr = ni * 16 + mrow;
                bh[ni] = *(const half8*)&Bh[nr * 128 + ((koct ^ (nr & 7)) * 8)];
            }
#pragma unroll
            for (int mi = 0; mi < 2; mi++)
#pragma unroll
                for (int ni = 0; ni < 3; ni++)
                    acc[mi][ni] = __builtin_amdgcn_mfma_f32_16x16x32_f16(ah[mi], bh[ni], acc[mi][ni], 0, 0, 0);
        }
    }

    // transposed store: kvout[b][h][d][f]
    float* kvp = kvout + (size_t)(b * NH_ + h) * FHD_ * HD_;
    float* ksp = ksum + (size_t)(b * NH_ + h) * FHD_;
#pragma unroll
    for (int mi = 0; mi < 2; mi++) {
        int mt = wv * 2 + mi;
#pragma unroll
        for (int r = 0; r < 4; r++) {
            int f = mt * 16 + kq * 4 + r;
            atomicAdd(&kvp[(size_t)mrow * FHD_ + f], acc[mi][0][r]);
            atomicAdd(&kvp[(size_t)(16 + mrow) * FHD_ + f], acc[mi][1][r]);
            if (mrow == 0) atomicAdd(&ksp[f], acc[mi][2][r]);
        }
    }
}

// ---------------------------------------------------------------- attention lookup via MFMA -> f16
__global__ __launch_bounds__(256) void attn_kernel(const _Float16* __restrict__ qbuf,
                                                   const float* __restrict__ kvin,
                                                   const float* __restrict__ ksum,
                                                   _Float16* __restrict__ ob) {
    __shared__ __align__(16) unsigned short Aq[128 * 40];
    __shared__ __align__(16) unsigned short Bk[48 * 128];
    __shared__ __align__(16) float tS[128][4];
    __shared__ float zS[128];

    const int chunk = blockIdx.x;
    const int h = blockIdx.y, b = blockIdx.z;
    const int t = threadIdx.x;
    const int n0 = chunk * 128;

    {
        const float* kvp = kvin + ((size_t)(b * NH_ + h)) * (HD_ * FHD_);
        int d = t >> 3;
        int c0 = (t & 7) * 2;
#pragma unroll
        for (int cc = 0; cc < 2; cc++) {
            int c = c0 + cc;
            const float* src = kvp + (size_t)d * FHD_ + c * 8;
            half8 hv;
#pragma unroll
            for (int i = 0; i < 8; i++) hv[i] = (_Float16)abs_clamp(src[i]);
            *(half8*)&Bk[d * 128 + ((c ^ (d & 7)) * 8)] = hv;
        }
        if (t < 16) {
            const float* ks = ksum + ((size_t)(b * NH_ + h)) * FHD_ + t * 8;
            half8 hv;
#pragma unroll
            for (int i = 0; i < 8; i++) hv[i] = (_Float16)ks[i];
            *(half8*)&Bk[32 * 128 + (t * 8)] = hv;
        } else {
            int idx = t - 16;
            int r = 33 + (idx >> 4), c = idx & 15;
            half8 z = {};
            *(half8*)&Bk[r * 128 + ((c ^ (r & 7)) * 8)] = z;
        }
    }
    {
        int tok = t >> 1, hf = t & 1;
        const _Float16* qp = qbuf + ((size_t)b * N_ + n0 + tok) * CF_ + h * HD_ + hf * 16;
        half8 a0 = *(const half8*)qp;
        half8 a1 = *(const half8*)(qp + 8);
        *(half8*)&Aq[tok * 40 + hf * 16] = a0;
        *(half8*)&Aq[tok * 40 + hf * 16 + 8] = a1;
    }
    if (t < 128) {
        int n = n0 + t;
        float aa = (PI2F / 64.f) * (float)(n >> 6);
        float ab = (PI2F / 64.f) * (float)(n & 63);
        tS[t][0] = cosf(aa); tS[t][1] = sinf(aa);
        tS[t][2] = cosf(ab); tS[t][3] = sinf(ab);
    }
    __syncthreads();

    const int lane = t & 63;
    const int wv = t >> 6;
    const int mrow = lane & 15;
    const int kq = lane >> 4;

    half8 ah[2];
#pragma unroll
    for (int mi = 0; mi < 2; mi++)
        ah[mi] = *(const half8*)&Aq[(wv * 32 + mi * 16 + mrow) * 40 + kq * 8];

    f32x4 acc[4][2][3];
#pragma unroll
    for (int tt = 0; tt < 4; tt++)
#pragma unroll
        for (int mi = 0; mi < 2; mi++)
#pragma unroll
            for (int ni = 0; ni < 3; ni++) acc[tt][mi][ni] = (f32x4){0.f, 0.f, 0.f, 0.f};

#pragma unroll
    for (int tt = 0; tt < 4; tt++) {
        half8 bh[3];
        int cpos = tt * 4 + kq;
#pragma unroll
        for (int ni = 0; ni < 3; ni++) {
            int row = ni * 16 + mrow;
            bh[ni] = *(const half8*)&Bk[row * 128 + ((cpos ^ (row & 7)) * 8)];
        }
#pragma unroll
        for (int mi = 0; mi < 2; mi++)
#pragma unroll
            for (int ni = 0; ni < 3; ni++)
                acc[tt][mi][ni] = __builtin_amdgcn_mfma_f32_16x16x32_f16(ah[mi], bh[ni], acc[tt][mi][ni], 0, 0, 0);
    }

    if (mrow == 0) {
#pragma unroll
        for (int mi = 0; mi < 2; mi++)
#pragma unroll
            for (int r = 0; r < 4; r++) {
                int tok = wv * 32 + mi * 16 + kq * 4 + r;
                float4 tv = *(const float4*)&tS[tok][0];
                float zraw = tv.x * acc[0][mi][2][r] + tv.y * acc[1][mi][2][r]
                           + tv.z * acc[2][mi][2][r] + tv.w * acc[3][mi][2][r];
                zS[tok] = abs_clamp(1.f / (zraw + EPS_));
            }
    }
    __syncthreads();

#pragma unroll
    for (int mi = 0; mi < 2; mi++) {
#pragma unroll
        for (int r = 0; r < 4; r++) {
            int tok = wv * 32 + mi * 16 + kq * 4 + r;
            float4 tv = *(const float4*)&tS[tok][0];
            float z = zS[tok];
            float v0 = tv.x * acc[0][mi][0][r] + tv.y * acc[1][mi][0][r]
                     + tv.z * acc[2][mi][0][r] + tv.w * acc[3][mi][0][r];
            float v1 = tv.x * acc[0][mi][1][r] + tv.y * acc[1][mi][1][r]
                     + tv.z * acc[2][mi][1][r] + tv.w * acc[3][mi][1][r];
            v0 = abs_clamp(abs_clamp(v0) * z);
            v1 = abs_clamp(abs_clamp(v1) * z);
            size_t base = ((size_t)b * N_ + n0 + tok) * CF_ + h * HD_;
            ob[base + mrow] = (_Float16)v0;
            ob[base + 16 + mrow] = (_Float16)v1;
        }
    }
}

// ----------------------------------------------------------------
extern "C" void kernel_launch(void* const* d_in, const int* in_sizes, int n_in,
                              void* d_out, int out_size, void* d_ws, size_t ws_size,
                              hipStream_t stream) {
    (void)in_sizes; (void)n_in; (void)out_size; (void)ws_size;
    const float* query = (const float*)d_in[0];
    const float* Wq = (const float*)d_in[1];
    const float* bq = (const float*)d_in[2];
    const float* Wk = (const float*)d_in[3];
    const float* bk = (const float*)d_in[4];
    const float* Wv = (const float*)d_in[5];
    const float* bv = (const float*)d_in[6];
    const float* Wo = (const float*)d_in[7];
    const float* bo = (const float*)d_in[8];
    const float* Wse1 = (const float*)d_in[9];
    const float* Wse2 = (const float*)d_in[10];
    float* out = (float*)d_out;

    unsigned char* ws = (unsigned char*)d_ws;
    const size_t MB = 1024ull * 1024ull;
    _Float16* q16 = (_Float16*)(ws + 0);
    _Float16* ob  = (_Float16*)(ws + 0);
    _Float16* qb  = (_Float16*)(ws + 64 * MB);   // [65536,256] f16
    _Float16* kbT = (_Float16*)(ws + 96 * MB);   // [256,65536] f16 (transposed)
    _Float16* vbT = (_Float16*)(ws + 128 * MB);  // [256,65536] f16 (transposed)
    _Float16* wcat = (_Float16*)(ws + 160 * MB);            // [768,512] f16
    _Float16* wo16 = (_Float16*)(ws + 160 * MB + 786432);   // [512,256] f16
    float* kvb = (float*)(ws + 161 * MB);                   // [16,8,32,128] f32
    float* ksb = (float*)(ws + 163 * MB);                   // [16,8,128]
    float* ssb = (float*)(ws + 163 * MB + 65536);           // [16,512]
    float* sgb = (float*)(ws + 163 * MB + 98304);           // [16,512]

    hipMemsetAsync(kvb, 0, 2097152 + 65536 + 32768, stream);

    convert_w<<<2048, 256, 0, stream>>>(Wq, Wk, Wv, Wo, wcat, wo16);
    se_sum_kernel<<<dim3(B_, 64), 256, 0, stream>>>(query, ssb, q16);
    se_gate_kernel<<<B_, 256, 0, stream>>>(ssb, Wse1, Wse2, sgb);
    gemm_qkv<<<dim3(6, 512), 256, 0, stream>>>(q16, wcat, bq, bk, bv, qb, kbT, vbT);
    kv_mfma_kernel<<<dim3(8, NH_, B_), 256, 0, stream>>>(kbT, vbT, kvb, ksb);
    attn_kernel<<<dim3(32, NH_, B_), 256, 0, stream>>>(qb, kvb, ksb, ob);
    gemm_out<<<dim3(4, 512), 256, 0, stream>>>(ob, wo16, bo, sgb, out);
}

// Round 7
// 499.799 us; speedup vs baseline: 1.0522x; 1.0522x over previous
//
#include <hip/hip_runtime.h>
#include <math.h>

#define B_   16
#define N_   4096
#define C_   512
#define CF_  256
#define NH_  8
#define HD_  32
#define FHD_ 128
#define BN_  (B_ * N_)   // 65536
#define EPS_ 1e-4f
#define PI2F 1.5707963267948966f

typedef _Float16 half8 __attribute__((ext_vector_type(8)));
typedef _Float16 half4 __attribute__((ext_vector_type(4)));
typedef float f32x4 __attribute__((ext_vector_type(4)));
typedef unsigned short u16x8 __attribute__((ext_vector_type(8)));

__device__ __forceinline__ float abs_clamp(float t) {
    float a = fminf(fmaxf(fabsf(t), 1e-4f), 1e4f);
    return t > 0.f ? a : (t < 0.f ? -a : 0.f);
}
__device__ __forceinline__ void gld16(const void* g, void* l) {
    __builtin_amdgcn_global_load_lds(
        (const __attribute__((address_space(1))) void*)g,
        (__attribute__((address_space(3))) void*)l, 16, 0, 0);
}

// ---------------------------------------------------------------- SE: mean over tokens + f32->f16 convert of query
__global__ __launch_bounds__(256) void se_sum_kernel(const float* __restrict__ q,
                                                     float* __restrict__ sesum,
                                                     _Float16* __restrict__ q16) {
    int b = blockIdx.x, chunk = blockIdx.y;   // chunk = 64 tokens
    int t = threadIdx.x;
    int c = (t & 127) * 4;
    int tok0 = chunk * 64 + (t >> 7) * 32;
    const float* p = q + ((size_t)b * N_ + tok0) * C_ + c;
    _Float16* o = q16 + ((size_t)b * N_ + tok0) * C_ + c;
    float a0 = 0.f, a1 = 0.f, a2 = 0.f, a3 = 0.f;
#pragma unroll 4
    for (int n = 0; n < 32; n++) {
        float4 v = *(const float4*)(p + (size_t)n * C_);
        a0 += v.x; a1 += v.y; a2 += v.z; a3 += v.w;
        half4 hv;
        hv[0] = (_Float16)v.x; hv[1] = (_Float16)v.y;
        hv[2] = (_Float16)v.z; hv[3] = (_Float16)v.w;
        *(half4*)(o + (size_t)n * C_) = hv;
    }
    atomicAdd(&sesum[b * C_ + c + 0], a0);
    atomicAdd(&sesum[b * C_ + c + 1], a1);
    atomicAdd(&sesum[b * C_ + c + 2], a2);
    atomicAdd(&sesum[b * C_ + c + 3], a3);
}

// ---------------------------------------------------------------- SE: 2-layer MLP + sigmoid
__global__ __launch_bounds__(256) void se_gate_kernel(const float* __restrict__ sesum,
                                                      const float* __restrict__ Wse1,
                                                      const float* __restrict__ Wse2,
                                                      float* __restrict__ segate) {
    __shared__ float sm[C_];
    __shared__ float hm[C_ / 2];
    int b = blockIdx.x, t = threadIdx.x;
    sm[t]       = sesum[b * C_ + t]       * (1.f / N_);
    sm[t + 256] = sesum[b * C_ + t + 256] * (1.f / N_);
    __syncthreads();
    {
        const float* w = Wse1 + (size_t)t * C_;
        float acc = 0.f;
        for (int c2 = 0; c2 < C_; c2++) acc += sm[c2] * w[c2];
        hm[t] = fmaxf(acc, 0.f);
    }
    __syncthreads();
    for (int r = 0; r < 2; r++) {
        int c2 = t + r * 256;
        const float* w2 = Wse2 + (size_t)c2 * (C_ / 2);
        float a2 = 0.f;
        for (int j = 0; j < C_ / 2; j++) a2 += hm[j] * w2[j];
        segate[b * C_ + c2] = 1.f / (1.f + expf(-a2));
    }
}

// ---------------------------------------------------------------- weight convert to f16
__global__ __launch_bounds__(256) void convert_w(const float* __restrict__ Wq,
                                                 const float* __restrict__ Wk,
                                                 const float* __restrict__ Wv,
                                                 const float* __restrict__ Wo,
                                                 _Float16* __restrict__ wcat,
                                                 _Float16* __restrict__ wo16) {
    int i = blockIdx.x * 256 + threadIdx.x;
    if (i < 768 * 512) {
        int r = i >> 9, c = i & 511;
        float w = (r < 256) ? Wq[(size_t)r * 512 + c]
                : (r < 512) ? Wk[(size_t)(r - 256) * 512 + c]
                            : Wv[(size_t)(r - 512) * 512 + c];
        wcat[i] = (_Float16)w;
    } else {
        int j = i - 768 * 512;
        wo16[j] = (_Float16)Wo[j];
    }
}

// ---------------------------------------------------------------- q/k/v projection GEMM
// 3-buffer LDS pipeline, counted vmcnt(4) + raw s_barrier (one per K-step).
__global__ __launch_bounds__(256) void gemm_qkv(
    const _Float16* __restrict__ A16, const _Float16* __restrict__ Bw,
    const float* __restrict__ bq, const float* __restrict__ bk, const float* __restrict__ bv,
    _Float16* __restrict__ Oq, _Float16* __restrict__ kT, _Float16* __restrict__ vT) {
    constexpr int K = 512;
    constexpr int NITER = K / 32;   // 16

    __shared__ __align__(16) unsigned short As[3][128 * 32];
    __shared__ __align__(16) unsigned short Bs[3][128 * 32];

    const int t = threadIdx.x;
    const int did = blockIdx.x + 6 * blockIdx.y;
    const int lid = (did & 7) * 384 + (did >> 3);
    const int bx = lid % 6;
    const int Mb = (lid / 6) * 128;
    const int nrow0 = bx * 128;

    const int lane = t & 63;
    const int wv = t >> 6;
    const int mq = (wv >> 1) * 64;
    const int nq = (wv & 1) * 64;
    const int mrow = lane & 15;
    const int kq = lane >> 4;
    const int fragoff = mrow * 32 + ((kq ^ ((mrow >> 1) & 3)) * 8);

    const unsigned char *asrc0, *asrc1, *bsrc0, *bsrc1;
    int off0, off1;
    {
        int cid0 = t, cid1 = t + 256;
        int m0 = cid0 >> 2, c0 = (cid0 & 3) ^ ((m0 >> 1) & 3);
        int m1 = cid1 >> 2, c1 = (cid1 & 3) ^ ((m1 >> 1) & 3);
        asrc0 = (const unsigned char*)(A16 + (size_t)(Mb + m0) * K + c0 * 8);
        asrc1 = (const unsigned char*)(A16 + (size_t)(Mb + m1) * K + c1 * 8);
        bsrc0 = (const unsigned char*)(Bw + (size_t)(nrow0 + m0) * K + c0 * 8);
        bsrc1 = (const unsigned char*)(Bw + (size_t)(nrow0 + m1) * K + c1 * 8);
        off0 = cid0 * 8;
        off1 = cid1 * 8;
    }

    f32x4 acc[4][4];
#pragma unroll
    for (int mi = 0; mi < 4; mi++)
#pragma unroll
        for (int ni = 0; ni < 4; ni++) acc[mi][ni] = (f32x4){0.f, 0.f, 0.f, 0.f};

    gld16(asrc0, &As[0][off0]);
    gld16(asrc1, &As[0][off1]);
    gld16(bsrc0, &Bs[0][off0]);
    gld16(bsrc1, &Bs[0][off1]);
    gld16(asrc0 + 64, &As[1][off0]);
    gld16(asrc1 + 64, &As[1][off1]);
    gld16(bsrc0 + 64, &Bs[1][off0]);
    gld16(bsrc1 + 64, &Bs[1][off1]);

    int cur = 0;
#pragma unroll 1
    for (int it = 0; it < NITER; ++it) {
        if (it + 1 < NITER) {
            asm volatile("s_waitcnt vmcnt(4)" ::: "memory");
        } else {
            asm volatile("s_waitcnt vmcnt(0)" ::: "memory");
        }
        __builtin_amdgcn_sched_barrier(0);
        __builtin_amdgcn_s_barrier();
        if (it + 2 < NITER) {
            int nb = cur + 2; if (nb >= 3) nb -= 3;
            gld16(asrc0 + (it + 2) * 64, &As[nb][off0]);
            gld16(asrc1 + (it + 2) * 64, &As[nb][off1]);
            gld16(bsrc0 + (it + 2) * 64, &Bs[nb][off0]);
            gld16(bsrc1 + (it + 2) * 64, &Bs[nb][off1]);
        }

        half8 ah[4], bh[4];
#pragma unroll
        for (int mi = 0; mi < 4; mi++)
            ah[mi] = *(const half8*)&As[cur][(mq + mi * 16) * 32 + fragoff];
#pragma unroll
        for (int ni = 0; ni < 4; ni++)
            bh[ni] = *(const half8*)&Bs[cur][(nq + ni * 16) * 32 + fragoff];
#pragma unroll
        for (int mi = 0; mi < 4; mi++)
#pragma unroll
            for (int ni = 0; ni < 4; ni++)
                acc[mi][ni] = __builtin_amdgcn_mfma_f32_16x16x32_f16(ah[mi], bh[ni], acc[mi][ni], 0, 0, 0);

        cur = (cur == 2) ? 0 : cur + 1;
    }

#pragma unroll
    for (int ni = 0; ni < 4; ni++) {
        int gc = nrow0 + nq + ni * 16 + mrow;
        int mat = gc >> 8;
        int col = gc & 255;
        float bb = (mat == 0 ? bq : mat == 1 ? bk : bv)[col];
        if (mat == 0) {
#pragma unroll
            for (int mi = 0; mi < 4; mi++)
#pragma unroll
                for (int r = 0; r < 4; r++) {
                    int m = Mb + mq + mi * 16 + kq * 4 + r;
                    float v2 = fmaxf(acc[mi][ni][r] + bb, 0.f);
                    Oq[(size_t)m * CF_ + col] = (_Float16)v2;
                }
        } else {
            _Float16* OT = (mat == 1) ? kT : vT;
#pragma unroll
            for (int mi = 0; mi < 4; mi++) {
                int m0r = Mb + mq + mi * 16 + kq * 4;
                half4 hv;
#pragma unroll
                for (int r = 0; r < 4; r++) {
                    float v2 = acc[mi][ni][r] + bb;
                    if (mat == 1) v2 = fmaxf(v2, 0.f);
                    hv[r] = (_Float16)v2;
                }
                *(half4*)&OT[(size_t)col * BN_ + m0r] = hv;
            }
        }
    }
}

// ---------------------------------------------------------------- output projection GEMM
__global__ __launch_bounds__(256) void gemm_out(
    const _Float16* __restrict__ A16, const _Float16* __restrict__ Bw,
    const float* __restrict__ bo, const float* __restrict__ sg,
    float* __restrict__ Of) {
    constexpr int K = 256;
    constexpr int NITER = K / 32;   // 8

    __shared__ __align__(16) unsigned short As[3][128 * 32];
    __shared__ __align__(16) unsigned short Bs[3][128 * 32];

    const int t = threadIdx.x;
    const int did = blockIdx.x + 4 * blockIdx.y;
    const int lid = (did & 7) * 256 + (did >> 3);
    const int bx = lid & 3;
    const int Mb = (lid >> 2) * 128;
    const int nrow0 = bx * 128;

    const int lane = t & 63;
    const int wv = t >> 6;
    const int mq = (wv >> 1) * 64;
    const int nq = (wv & 1) * 64;
    const int mrow = lane & 15;
    const int kq = lane >> 4;
    const int fragoff = mrow * 32 + ((kq ^ ((mrow >> 1) & 3)) * 8);

    const unsigned char *asrc0, *asrc1, *bsrc0, *bsrc1;
    int off0, off1;
    {
        int cid0 = t, cid1 = t + 256;
        int m0 = cid0 >> 2, c0 = (cid0 & 3) ^ ((m0 >> 1) & 3);
        int m1 = cid1 >> 2, c1 = (cid1 & 3) ^ ((m1 >> 1) & 3);
        asrc0 = (const unsigned char*)(A16 + (size_t)(Mb + m0) * K + c0 * 8);
        asrc1 = (const unsigned char*)(A16 + (size_t)(Mb + m1) * K + c1 * 8);
        bsrc0 = (const unsigned char*)(Bw + (size_t)(nrow0 + m0) * K + c0 * 8);
        bsrc1 = (const unsigned char*)(Bw + (size_t)(nrow0 + m1) * K + c1 * 8);
        off0 = cid0 * 8;
        off1 = cid1 * 8;
    }

    f32x4 acc[4][4];
#pragma unroll
    for (int mi = 0; mi < 4; mi++)
#pragma unroll
        for (int ni = 0; ni < 4; ni++) acc[mi][ni] = (f32x4){0.f, 0.f, 0.f, 0.f};

    gld16(asrc0, &As[0][off0]);
    gld16(asrc1, &As[0][off1]);
    gld16(bsrc0, &Bs[0][off0]);
    gld16(bsrc1, &Bs[0][off1]);
    gld16(asrc0 + 64, &As[1][off0]);
    gld16(asrc1 + 64, &As[1][off1]);
    gld16(bsrc0 + 64, &Bs[1][off0]);
    gld16(bsrc1 + 64, &Bs[1][off1]);

    int cur = 0;
#pragma unroll 1
    for (int it = 0; it < NITER; ++it) {
        if (it + 1 < NITER) {
            asm volatile("s_waitcnt vmcnt(4)" ::: "memory");
        } else {
            asm volatile("s_waitcnt vmcnt(0)" ::: "memory");
        }
        __builtin_amdgcn_sched_barrier(0);
        __builtin_amdgcn_s_barrier();
        if (it + 2 < NITER) {
            int nb = cur + 2; if (nb >= 3) nb -= 3;
            gld16(asrc0 + (it + 2) * 64, &As[nb][off0]);
            gld16(asrc1 + (it + 2) * 64, &As[nb][off1]);
            gld16(bsrc0 + (it + 2) * 64, &Bs[nb][off0]);
            gld16(bsrc1 + (it + 2) * 64, &Bs[nb][off1]);
        }

        half8 ah[4], bh[4];
#pragma unroll
        for (int mi = 0; mi < 4; mi++)
            ah[mi] = *(const half8*)&As[cur][(mq + mi * 16) * 32 + fragoff];
#pragma unroll
        for (int ni = 0; ni < 4; ni++)
            bh[ni] = *(const half8*)&Bs[cur][(nq + ni * 16) * 32 + fragoff];
#pragma unroll
        for (int mi = 0; mi < 4; mi++)
#pragma unroll
            for (int ni = 0; ni < 4; ni++)
                acc[mi][ni] = __builtin_amdgcn_mfma_f32_16x16x32_f16(ah[mi], bh[ni], acc[mi][ni], 0, 0, 0);

        cur = (cur == 2) ? 0 : cur + 1;
    }

    int b = Mb >> 12;
#pragma unroll
    for (int ni = 0; ni < 4; ni++) {
        int gc = nrow0 + nq + ni * 16 + mrow;
        float bb = bo[gc];
        float gv = sg[b * C_ + gc];
#pragma unroll
        for (int mi = 0; mi < 4; mi++)
#pragma unroll
            for (int r = 0; r < 4; r++) {
                int m = Mb + mq + mi * 16 + kq * 4 + r;
                float v2 = abs_clamp(acc[mi][ni][r] + bb);
                v2 = abs_clamp(v2 * (1.f + gv));
                Of[(size_t)m * C_ + gc] = v2;
            }
    }
}

// ---------------------------------------------------------------- kv partials via f16 MFMA (NO atomics)
// Block = (slab of 256 tokens, h, b); 2 chunks of 128 tokens. LDS row stride
// 136 u16 (272 B, 16B-aligned, bank = 4*row): conflicts <= 4-way vs previous
// 8-way. Partials plain-stored to pkv[slab][bh][f*32+d] / pks[slab][bh][f].
#define AST 136
__global__ __launch_bounds__(256) void kv_partial_kernel(const _Float16* __restrict__ kin,
                                                         const _Float16* __restrict__ vin,
                                                         float* __restrict__ pkv,
                                                         float* __restrict__ pks) {
    __shared__ __align__(16) unsigned short Ah[128 * AST];   // 34 KB
    __shared__ __align__(16) unsigned short Bh[48 * AST];    // 12.75 KB

    const int t = threadIdx.x;
    const int c8 = blockIdx.x;           // 0..15, 256-token slab
    const int h = blockIdx.y, b = blockIdx.z;
    const int dp = t & 31;               // channel within head
    const int oct = t >> 5;              // token octet 0..7

    // constant rows 32..47: row 32 = ones(f16), rest zero
    {
        int r = 32 + (t >> 4);
        int c = t & 15;
        unsigned short fill = (r == 32) ? (unsigned short)0x3C00 : (unsigned short)0;
        u16x8 z = {fill, fill, fill, fill, fill, fill, fill, fill};
        *(u16x8*)&Bh[r * AST + c * 8] = z;
    }

    float cbv[8], sbv[8];
#pragma unroll
    for (int i = 0; i < 8; i++) {
        float ang = (PI2F / 64.f) * (float)(oct * 8 + i);
        cbv[i] = cosf(ang);
        sbv[i] = sinf(ang);
    }

    const int lane = t & 63;
    const int wv = t >> 6;
    const int mrow = lane & 15;
    const int kq = lane >> 4;

    f32x4 acc[2][3];
#pragma unroll
    for (int mi = 0; mi < 2; mi++)
#pragma unroll
        for (int ni = 0; ni < 3; ni++) acc[mi][ni] = (f32x4){0.f, 0.f, 0.f, 0.f};

    const size_t colbase = (size_t)(h * HD_ + dp) * BN_ + (size_t)b * N_;
    const _Float16* kp0 = kin + colbase + c8 * 256 + oct * 8;
    const _Float16* vp0 = vin + colbase + c8 * 256 + oct * 8;

    // upfront loads: 2 chunks x 2 half8 each for k and v (32 VGPRs)
    half8 kk[2][2], vv[2][2];
#pragma unroll
    for (int ch = 0; ch < 2; ch++) {
        kk[ch][0] = *(const half8*)(kp0 + ch * 128);
        kk[ch][1] = *(const half8*)(kp0 + ch * 128 + 64);
        vv[ch][0] = *(const half8*)(vp0 + ch * 128);
        vv[ch][1] = *(const half8*)(vp0 + ch * 128 + 64);
    }

#pragma unroll
    for (int ch = 0; ch < 2; ch++) {
        const int n0 = c8 * 256 + ch * 128;
        const int rr = n0 >> 6;
        float ca0 = cosf((PI2F / 64.f) * (float)rr),       sa0 = sinf((PI2F / 64.f) * (float)rr);
        float ca1 = cosf((PI2F / 64.f) * (float)(rr + 1)), sa1 = sinf((PI2F / 64.f) * (float)(rr + 1));

        float ka[8], kb[8];
#pragma unroll
        for (int i = 0; i < 8; i++) { ka[i] = (float)kk[ch][0][i]; kb[i] = (float)kk[ch][1][i]; }

        __syncthreads();   // previous chunk's fragment reads done

#pragma unroll
        for (int tvar = 0; tvar < 4; tvar++) {
            int f = tvar * 32 + dp;
            half8 ha, hb;
#pragma unroll
            for (int i = 0; i < 8; i++) {
                float fa = (tvar == 0) ? ca0 : (tvar == 1) ? sa0 : (tvar == 2) ? cbv[i] : sbv[i];
                float fb = (tvar == 0) ? ca1 : (tvar == 1) ? sa1 : (tvar == 2) ? cbv[i] : sbv[i];
                ha[i] = (_Float16)(ka[i] * fa);
                hb[i] = (_Float16)(kb[i] * fb);
            }
            *(half8*)&Ah[f * AST + oct * 8] = ha;          // tokens 0..63 of chunk
            *(half8*)&Ah[f * AST + 64 + oct * 8] = hb;     // tokens 64..127
        }
        *(half8*)&Bh[dp * AST + oct * 8] = vv[ch][0];
        *(half8*)&Bh[dp * AST + 64 + oct * 8] = vv[ch][1];
        __syncthreads();

#pragma unroll
        for (int s = 0; s < 4; s++) {
            int coff = (s * 4 + kq) * 8;
            half8 ah[2], bh[3];
#pragma unroll
            for (int mi = 0; mi < 2; mi++) {
                int f = (wv * 2 + mi) * 16 + mrow;
                ah[mi] = *(const half8*)&Ah[f * AST + coff];
            }
#pragma unroll
            for (int ni = 0; ni < 3; ni++) {
                int nr = ni * 16 + mrow;
                bh[ni] = *(const half8*)&Bh[nr * AST + coff];
            }
#pragma unroll
            for (int mi = 0; mi < 2; mi++)
#pragma unroll
                for (int ni = 0; ni < 3; ni++)
                    acc[mi][ni] = __builtin_amdgcn_mfma_f32_16x16x32_f16(ah[mi], bh[ni], acc[mi][ni], 0, 0, 0);
        }
    }

    // plain partial stores
    const int bh = b * NH_ + h;
    float* pv = pkv + ((size_t)c8 * 128 + bh) * (FHD_ * HD_);
    float* ps = pks + ((size_t)c8 * 128 + bh) * FHD_;
#pragma unroll
    for (int mi = 0; mi < 2; mi++) {
        int mt = wv * 2 + mi;
#pragma unroll
        for (int r = 0; r < 4; r++) {
            int f = mt * 16 + kq * 4 + r;
            pv[(size_t)f * HD_ + mrow] = acc[mi][0][r];
            pv[(size_t)f * HD_ + 16 + mrow] = acc[mi][1][r];
            if (mrow == 0) ps[f] = acc[mi][2][r];
        }
    }
}

// ---------------------------------------------------------------- kv reduce: sum 16 slab partials
// Output kvout[b][h][d=32][f=128] (transposed, the attn B-operand layout) + ksum.
__global__ __launch_bounds__(256) void kv_reduce_kernel(const float* __restrict__ pkv,
                                                        const float* __restrict__ pks,
                                                        float* __restrict__ kvout,
                                                        float* __restrict__ ksum) {
    const int bh = blockIdx.x;      // 0..127
    const int part = blockIdx.y;    // 0..7
    const int t = threadIdx.x;
#pragma unroll
    for (int i = 0; i < 2; i++) {
        int e = t + (part * 2 + i) * 256;   // 0..4095 = f*32+d
        float s = 0.f;
#pragma unroll 4
        for (int sl = 0; sl < 16; sl++)
            s += pkv[((size_t)sl * 128 + bh) * (FHD_ * HD_) + e];
        int f = e >> 5, d = e & 31;
        kvout[(size_t)bh * (FHD_ * HD_) + (size_t)d * FHD_ + f] = s;   // transposed [d][f]
    }
    if (part == 0 && t < 128) {
        float s = 0.f;
#pragma unroll 4
        for (int sl = 0; sl < 16; sl++)
            s += pks[((size_t)sl * 128 + bh) * FHD_ + t];
        ksum[bh * FHD_ + t] = s;
    }
}

// ---------------------------------------------------------------- attention lookup via MFMA -> f16
__global__ __launch_bounds__(256) void attn_kernel(const _Float16* __restrict__ qbuf,
                                                   const float* __restrict__ kvin,
                                                   const float* __restrict__ ksum,
                                                   _Float16* __restrict__ ob) {
    __shared__ __align__(16) unsigned short Aq[128 * 40];
    __shared__ __align__(16) unsigned short Bk[48 * 128];
    __shared__ __align__(16) float tS[128][4];
    __shared__ float zS[128];

    const int chunk = blockIdx.x;
    const int h = blockIdx.y, b = blockIdx.z;
    const int t = threadIdx.x;
    const int n0 = chunk * 128;

    {
        const float* kvp = kvin + ((size_t)(b * NH_ + h)) * (HD_ * FHD_);
        int d = t >> 3;
        int c0 = (t & 7) * 2;
#pragma unroll
        for (int cc = 0; cc < 2; cc++) {
            int c = c0 + cc;
            const float* src = kvp + (size_t)d * FHD_ + c * 8;
            half8 hv;
#pragma unroll
            for (int i = 0; i < 8; i++) hv[i] = (_Float16)abs_clamp(src[i]);
            *(half8*)&Bk[d * 128 + ((c ^ (d & 7)) * 8)] = hv;
        }
        if (t < 16) {
            const float* ks = ksum + ((size_t)(b * NH_ + h)) * FHD_ + t * 8;
            half8 hv;
#pragma unroll
            for (int i = 0; i < 8; i++) hv[i] = (_Float16)ks[i];
            *(half8*)&Bk[32 * 128 + (t * 8)] = hv;
        } else {
            int idx = t - 16;
            int r = 33 + (idx >> 4), c = idx & 15;
            half8 z = {};
            *(half8*)&Bk[r * 128 + ((c ^ (r & 7)) * 8)] = z;
        }
    }
    {
        int tok = t >> 1, hf = t & 1;
        const _Float16* qp = qbuf + ((size_t)b * N_ + n0 + tok) * CF_ + h * HD_ + hf * 16;
        half8 a0 = *(const half8*)qp;
        half8 a1 = *(const half8*)(qp + 8);
        *(half8*)&Aq[tok * 40 + hf * 16] = a0;
        *(half8*)&Aq[tok * 40 + hf * 16 + 8] = a1;
    }
    if (t < 128) {
        int n = n0 + t;
        float aa = (PI2F / 64.f) * (float)(n >> 6);
        float ab = (PI2F / 64.f) * (float)(n & 63);
        tS[t][0] = cosf(aa); tS[t][1] = sinf(aa);
        tS[t][2] = cosf(ab); tS[t][3] = sinf(ab);
    }
    __syncthreads();

    const int lane = t & 63;
    const int wv = t >> 6;
    const int mrow = lane & 15;
    const int kq = lane >> 4;

    half8 ah[2];
#pragma unroll
    for (int mi = 0; mi < 2; mi++)
        ah[mi] = *(const half8*)&Aq[(wv * 32 + mi * 16 + mrow) * 40 + kq * 8];

    f32x4 acc[4][2][3];
#pragma unroll
    for (int tt = 0; tt < 4; tt++)
#pragma unroll
        for (int mi = 0; mi < 2; mi++)
#pragma unroll
            for (int ni = 0; ni < 3; ni++) acc[tt][mi][ni] = (f32x4){0.f, 0.f, 0.f, 0.f};

#pragma unroll
    for (int tt = 0; tt < 4; tt++) {
        half8 bh[3];
        int cpos = tt * 4 + kq;
#pragma unroll
        for (int ni = 0; ni < 3; ni++) {
            int row = ni * 16 + mrow;
            bh[ni] = *(const half8*)&Bk[row * 128 + ((cpos ^ (row & 7)) * 8)];
        }
#pragma unroll
        for (int mi = 0; mi < 2; mi++)
#pragma unroll
            for (int ni = 0; ni < 3; ni++)
                acc[tt][mi][ni] = __builtin_amdgcn_mfma_f32_16x16x32_f16(ah[mi], bh[ni], acc[tt][mi][ni], 0, 0, 0);
    }

    if (mrow == 0) {
#pragma unroll
        for (int mi = 0; mi < 2; mi++)
#pragma unroll
            for (int r = 0; r < 4; r++) {
                int tok = wv * 32 + mi * 16 + kq * 4 + r;
                float4 tv = *(const float4*)&tS[tok][0];
                float zraw = tv.x * acc[0][mi][2][r] + tv.y * acc[1][mi][2][r]
                           + tv.z * acc[2][mi][2][r] + tv.w * acc[3][mi][2][r];
                zS[tok] = abs_clamp(1.f / (zraw + EPS_));
            }
    }
    __syncthreads();

#pragma unroll
    for (int mi = 0; mi < 2; mi++) {
#pragma unroll
        for (int r = 0; r < 4; r++) {
            int tok = wv * 32 + mi * 16 + kq * 4 + r;
            float4 tv = *(const float4*)&tS[tok][0];
            float z = zS[tok];
            float v0 = tv.x * acc[0][mi][0][r] + tv.y * acc[1][mi][0][r]
                     + tv.z * acc[2][mi][0][r] + tv.w * acc[3][mi][0][r];
            float v1 = tv.x * acc[0][mi][1][r] + tv.y * acc[1][mi][1][r]
                     + tv.z * acc[2][mi][1][r] + tv.w * acc[3][mi][1][r];
            v0 = abs_clamp(abs_clamp(v0) * z);
            v1 = abs_clamp(abs_clamp(v1) * z);
            size_t base = ((size_t)b * N_ + n0 + tok) * CF_ + h * HD_;
            ob[base + mrow] = (_Float16)v0;
            ob[base + 16 + mrow] = (_Float16)v1;
        }
    }
}

// ----------------------------------------------------------------
extern "C" void kernel_launch(void* const* d_in, const int* in_sizes, int n_in,
                              void* d_out, int out_size, void* d_ws, size_t ws_size,
                              hipStream_t stream) {
    (void)in_sizes; (void)n_in; (void)out_size; (void)ws_size;
    const float* query = (const float*)d_in[0];
    const float* Wq = (const float*)d_in[1];
    const float* bq = (const float*)d_in[2];
    const float* Wk = (const float*)d_in[3];
    const float* bk = (const float*)d_in[4];
    const float* Wv = (const float*)d_in[5];
    const float* bv = (const float*)d_in[6];
    const float* Wo = (const float*)d_in[7];
    const float* bo = (const float*)d_in[8];
    const float* Wse1 = (const float*)d_in[9];
    const float* Wse2 = (const float*)d_in[10];
    float* out = (float*)d_out;

    unsigned char* ws = (unsigned char*)d_ws;
    const size_t MB = 1024ull * 1024ull;
    // Region ws+0..64MiB is time-shared (single stream serializes):
    //   q16  [65536,512] f16 (64 MiB)  written by se_sum, read by gemm_qkv
    //   pkv  [16][128][4096] f32 (32 MiB) + pks (1 MiB)  written by kv_partial
    //        (q16 dead), read by kv_reduce
    //   ob   [65536,256] f16 (32 MiB)  written by attn (pkv dead), read by gemm_out
    _Float16* q16 = (_Float16*)(ws + 0);
    float*    pkv = (float*)(ws + 0);
    float*    pks = (float*)(ws + 32 * MB);
    _Float16* ob  = (_Float16*)(ws + 0);
    _Float16* qb  = (_Float16*)(ws + 64 * MB);   // [65536,256] f16
    _Float16* kbT = (_Float16*)(ws + 96 * MB);   // [256,65536] f16 (transposed)
    _Float16* vbT = (_Float16*)(ws + 128 * MB);  // [256,65536] f16 (transposed)
    _Float16* wcat = (_Float16*)(ws + 160 * MB);            // [768,512] f16
    _Float16* wo16 = (_Float16*)(ws + 160 * MB + 786432);   // [512,256] f16
    float* kvb = (float*)(ws + 161 * MB);                   // [16,8,32,128] f32
    float* ksb = (float*)(ws + 163 * MB);                   // [16,8,128]
    float* ssb = (float*)(ws + 163 * MB + 65536);           // [16,512]
    float* sgb = (float*)(ws + 163 * MB + 98304);           // [16,512]

    hipMemsetAsync(ssb, 0, 32768, stream);

    convert_w<<<2048, 256, 0, stream>>>(Wq, Wk, Wv, Wo, wcat, wo16);
    se_sum_kernel<<<dim3(B_, 64), 256, 0, stream>>>(query, ssb, q16);
    se_gate_kernel<<<B_, 256, 0, stream>>>(ssb, Wse1, Wse2, sgb);
    gemm_qkv<<<dim3(6, 512), 256, 0, stream>>>(q16, wcat, bq, bk, bv, qb, kbT, vbT);
    kv_partial_kernel<<<dim3(16, NH_, B_), 256, 0, stream>>>(kbT, vbT, pkv, pks);
    kv_reduce_kernel<<<dim3(128, 8), 256, 0, stream>>>(pkv, pks, kvb, ksb);
    attn_kernel<<<dim3(32, NH_, B_), 256, 0, stream>>>(qb, kvb, ksb, ob);
    gemm_out<<<dim3(4, 512), 256, 0, stream>>>(ob, wo16, bo, sgb, out);
}